// Round 16
// baseline (154.719 us; speedup 1.0000x reference)
//
#include <hip/hip_runtime.h>

#define D 256
#define TPB 1024
#define SLOTS 32

__device__ __forceinline__ unsigned bfbits(float f) {  // f32 -> bf16 bits, RNE
    unsigned u = __float_as_uint(f);
    return (u + 0x7fffu + ((u >> 16) & 1u)) >> 16;
}
__device__ __forceinline__ float bflo(unsigned u) { return __uint_as_float(u << 16); }
__device__ __forceinline__ float bfhi(unsigned u) { return __uint_as_float(u & 0xffff0000u); }

// One block per segment; fully independent (no cross-block communication).
// Phase 0: streaming mean (1-ahead pipelined) + f32->bf16 convert into xb.
// Phases 1-3: w = exp(<x_i,S>) (shift-free; |alpha| bounded ~40 << f32
// overflow, eps form identical to reference) -> weighted mean -> squash -> S.
template<int USE_WS>
__global__ __launch_bounds__(TPB, 8)   // 2 blocks/CU -> 100% occupancy
void fused_k(const float* __restrict__ x, unsigned short* __restrict__ xb,
             const int* __restrict__ batch, float* __restrict__ out, int n)
{
    __shared__ float zp[SLOTS][D];   // 32 KB slot partials
    __shared__ float qp[4][D];       // 4 KB quarter-fold
    __shared__ float sp[SLOTS];
    __shared__ float zs[D];
    __shared__ float red[2];
    __shared__ float red_e[4];
    __shared__ int bnd[2];

    const int tid  = threadIdx.x;
    const int s    = blockIdx.x;
    const int slot = tid >> 5;       // 0..31 half-wave row-slots
    const int l    = tid & 31;       // col group: cols l*8..l*8+7
    const int wv   = tid >> 6;       // wave 0..15
    const int q    = tid >> 8;       // quarter 0..3
    const int col  = tid & 255;

    if (tid < 2) {                   // lower_bound(batch, s+tid); L2-cached
        const int key = s + tid;
        int lo = 0, hi = n;
        while (lo < hi) { int mid = (lo + hi) >> 1; if (batch[mid] < key) lo = mid + 1; else hi = mid; }
        bnd[tid] = lo;
    }
    __syncthreads();
    const int start = bnd[0];
    const int cnt   = bnd[1] - start;

    float Scol = 0.f;                // running S for column tid (tid < D)
    float zr[8] = {0,0,0,0,0,0,0,0};
    float z = 0.f;

    for (int ph = 0; ph < 4; ++ph) {
        float za[8] = {0,0,0,0,0,0,0,0};
        float s_acc = 0.f;

        if (ph == 0) {
            // streaming mean + f32->bf16 conversion, 1-ahead pipelined
            int r = slot;
            bool v = r < cnt;
            float4 c0 = {0,0,0,0}, c1 = {0,0,0,0};
            if (v) {
                const size_t o = (size_t)(start + r) * D + l * 8;
                c0 = *(const float4*)(x + o); c1 = *(const float4*)(x + o + 4);
            }
            while (v) {
                const int rn = r + SLOTS;
                const bool vn = rn < cnt;
                float4 n0 = {0,0,0,0}, n1 = {0,0,0,0};
                if (vn) {
                    const size_t o = (size_t)(start + rn) * D + l * 8;
                    n0 = *(const float4*)(x + o); n1 = *(const float4*)(x + o + 4);
                }
                const size_t boff = (size_t)(start + r) * D + l * 8;
                if (USE_WS) {
                    uint4 p;
                    p.x = bfbits(c0.x) | (bfbits(c0.y) << 16);
                    p.y = bfbits(c0.z) | (bfbits(c0.w) << 16);
                    p.z = bfbits(c1.x) | (bfbits(c1.y) << 16);
                    p.w = bfbits(c1.z) | (bfbits(c1.w) << 16);
                    *(uint4*)(xb + boff) = p;          // keep xb hot for phases
                }
                s_acc += 1.f;
                za[0] += c0.x; za[1] += c0.y; za[2] += c0.z; za[3] += c0.w;
                za[4] += c1.x; za[5] += c1.y; za[6] += c1.z; za[7] += c1.w;
                c0 = n0; c1 = n1; r = rn; v = vn;
            }
        } else {
            // weighted stream with 1-ahead prefetch
            int r = slot;
            uint4 ucur = make_uint4(0,0,0,0);
            float4 c0 = {0,0,0,0}, c1 = {0,0,0,0};
            if (r < cnt) {
                const size_t o = (size_t)(start + r) * D + l * 8;
                if (USE_WS) ucur = *(const uint4*)(xb + o);
                else { c0 = *(const float4*)(x + o); c1 = *(const float4*)(x + o + 4); }
            }
            while (r < cnt) {
                const int rn = r + SLOTS;
                uint4 unxt = make_uint4(0,0,0,0);
                float4 n0 = {0,0,0,0}, n1 = {0,0,0,0};
                if (rn < cnt) {
                    const size_t o = (size_t)(start + rn) * D + l * 8;
                    if (USE_WS) unxt = *(const uint4*)(xb + o);
                    else { n0 = *(const float4*)(x + o); n1 = *(const float4*)(x + o + 4); }
                }
                float xf[8];
                if (USE_WS) {
                    xf[0]=bflo(ucur.x); xf[1]=bfhi(ucur.x); xf[2]=bflo(ucur.y); xf[3]=bfhi(ucur.y);
                    xf[4]=bflo(ucur.z); xf[5]=bfhi(ucur.z); xf[6]=bflo(ucur.w); xf[7]=bfhi(ucur.w);
                } else {
                    xf[0]=c0.x; xf[1]=c0.y; xf[2]=c0.z; xf[3]=c0.w;
                    xf[4]=c1.x; xf[5]=c1.y; xf[6]=c1.z; xf[7]=c1.w;
                }
                float dt = 0.f;
#pragma unroll
                for (int j = 0; j < 8; ++j) dt += xf[j] * zr[j];
#pragma unroll
                for (int o = 16; o; o >>= 1) dt += __shfl_xor(dt, o);   // 32-lane half
                const float w = __expf(dt);
                s_acc += w;
#pragma unroll
                for (int j = 0; j < 8; ++j) za[j] += w * xf[j];
                ucur = unxt; c0 = n0; c1 = n1; r = rn;
            }
        }

        // ---- fold: 32 slot-partials -> z (all 1024 threads), weight-sum via wave 0 ----
#pragma unroll
        for (int j = 0; j < 8; ++j) zp[slot][l * 8 + j] = za[j];
        if (l == 0) sp[slot] = s_acc;
        __syncthreads();
        {
            float p = 0.f;
#pragma unroll
            for (int h = 0; h < 8; ++h) p += zp[q * 8 + h][col];
            qp[q][col] = p;
            if (tid < 32) {
                float st = sp[tid];
#pragma unroll
                for (int o = 16; o; o >>= 1) st += __shfl_xor(st, o);
                if (tid == 0) red[0] = 1.f / (st + 1e-16f);
            }
        }
        __syncthreads();
        if (tid < D) z = (qp[0][tid] + qp[1][tid] + qp[2][tid] + qp[3][tid]) * red[0];

        if (ph == 3) {
            if (tid < D) out[(size_t)s * D + tid] = z;
            break;
        }

        // ---- energy + squash; S += squash(z) ----
        float e = (tid < D) ? z * z : 0.f;
#pragma unroll
        for (int o = 32; o; o >>= 1) e += __shfl_xor(e, o);
        if ((tid & 63) == 0 && wv < 4) red_e[wv] = e;
        __syncthreads();
        if (tid == 0) {
            const float E = red_e[0] + red_e[1] + red_e[2] + red_e[3];
            red[1] = (E > 0.f) ? (sqrtf(E) / (1.f + E)) : 0.f;
        }
        __syncthreads();
        if (tid < D) { Scol += z * red[1]; zs[tid] = Scol; }
        __syncthreads();
#pragma unroll
        for (int j = 0; j < 8; ++j) zr[j] = zs[l * 8 + j];
    }
}

extern "C" void kernel_launch(void* const* d_in, const int* in_sizes, int n_in,
                              void* d_out, int out_size, void* d_ws, size_t ws_size,
                              hipStream_t stream) {
    const float* x   = (const float*)d_in[0];
    const int* batch = (const int*)d_in[1];
    float* out       = (float*)d_out;
    const int n = in_sizes[1];          // 262144
    const int B = out_size / D;         // 512

    const size_t xb_bytes = (size_t)n * D * sizeof(unsigned short);      // 134 MB
    const bool use_ws = ws_size >= xb_bytes;
    unsigned short* xb = (unsigned short*)d_ws;

    if (use_ws) fused_k<1><<<B, TPB, 0, stream>>>(x, xb, batch, out, n);
    else        fused_k<0><<<B, TPB, 0, stream>>>(x, xb, batch, out, n);
}

// Round 17
// 143.126 us; speedup vs baseline: 1.0810x; 1.0810x over previous
//
#include <hip/hip_runtime.h>

#define D 256
#define CPS 4            // pass0 chunk-blocks per segment
#define TPB0 256
#define TPB1 1024        // phases kernel: 1 block/segment, 32 half-wave row-slots
#define SLOTS 32
#define PSTR (D + 1)

__device__ __forceinline__ unsigned bfbits(float f) {  // f32 -> bf16 bits, RNE
    unsigned u = __float_as_uint(f);
    return (u + 0x7fffu + ((u >> 16) & 1u)) >> 16;
}
__device__ __forceinline__ float bflo(unsigned u) { return __uint_as_float(u << 16); }
__device__ __forceinline__ float bfhi(unsigned u) { return __uint_as_float(u & 0xffff0000u); }

// ---------- kernel 1: pass 0 — mean partials + f32->bf16 conversion ----------
template<int USE_WS>
__global__ __launch_bounds__(TPB0, 8)
void pass0_k(const float* __restrict__ x, unsigned short* __restrict__ xb,
             const int* __restrict__ batch, float* __restrict__ part_out, int n)
{
    __shared__ float zp[8][D];
    __shared__ float sp[8];
    __shared__ int bnd[2];
    const int tid = threadIdx.x;
    const int s = blockIdx.x / CPS, k = blockIdx.x % CPS;
    const int hw = tid >> 5, l = tid & 31;

    if (tid < 2) {                       // lower_bound(batch, s+tid); L2-cached
        const int key = s + tid;
        int lo = 0, hi = n;
        while (lo < hi) { int mid = (lo + hi) >> 1; if (batch[mid] < key) lo = mid + 1; else hi = mid; }
        bnd[tid] = lo;
    }
    __syncthreads();
    const int start = bnd[0];
    const int cnt   = bnd[1] - start;
    const int csz   = (cnt + CPS - 1) / CPS;
    const int rbeg  = k * csz;
    const int rend  = min(cnt, rbeg + csz);

    float za[8] = {0,0,0,0,0,0,0,0};
    float s_acc = 0.f;
#pragma unroll 2
    for (int r = rbeg + hw; r < rend; r += 8) {
        const size_t boff = (size_t)(start + r) * D + l * 8;
        const float4 v0 = *(const float4*)(x + boff);
        const float4 v1 = *(const float4*)(x + boff + 4);
        if (USE_WS) {
            uint4 p;
            p.x = bfbits(v0.x) | (bfbits(v0.y) << 16);
            p.y = bfbits(v0.z) | (bfbits(v0.w) << 16);
            p.z = bfbits(v1.x) | (bfbits(v1.y) << 16);
            p.w = bfbits(v1.z) | (bfbits(v1.w) << 16);
            *(uint4*)(xb + boff) = p;
        }
        s_acc += 1.f;
        za[0] += v0.x; za[1] += v0.y; za[2] += v0.z; za[3] += v0.w;
        za[4] += v1.x; za[5] += v1.y; za[6] += v1.z; za[7] += v1.w;
    }
#pragma unroll
    for (int j = 0; j < 8; ++j) zp[hw][l * 8 + j] = za[j];
    if (l == 0) sp[hw] = s_acc;
    __syncthreads();
    float acc = 0.f;
#pragma unroll
    for (int h = 0; h < 8; ++h) acc += zp[h][tid];
    float* po = part_out + (size_t)(s * CPS + k) * PSTR;
    po[tid] = acc;
    if (tid == 0) {
        float st = 0.f;
#pragma unroll
        for (int h = 0; h < 8; ++h) st += sp[h];
        po[D] = st;
    }
}

// ---------- kernel 2: phases 1-3 + output, one 1024-thread block per segment ----
// Folds pass0 partials -> z0, then 3x (squash -> weighted stream -> fold) fully
// in-block. w = exp(<x_i,S>) shift-free (|alpha| bounded ~30 << f32 overflow;
// eps form identical to reference). 512 blocks @ 2/CU = 100% occupancy.
template<int USE_WS>
__global__ __launch_bounds__(TPB1, 8)
void phases_k(const float* __restrict__ x, const unsigned short* __restrict__ xb,
              const int* __restrict__ batch,
              const float* __restrict__ part, float* __restrict__ out, int n)
{
    __shared__ float zp[SLOTS][D];   // 32 KB
    __shared__ float sp[SLOTS];
    __shared__ float zs[D];
    __shared__ float red_e[16];
    __shared__ float red[2];
    __shared__ int bnd[2];
    const int tid  = threadIdx.x;
    const int s    = blockIdx.x;
    const int slot = tid >> 5;    // 0..31 row-slots (half-waves)
    const int l    = tid & 31;    // col group: cols l*8..l*8+7
    const int wv   = tid >> 6;    // 0..15

    if (tid < 2) {
        const int key = s + tid;
        int lo = 0, hi = n;
        while (lo < hi) { int mid = (lo + hi) >> 1; if (batch[mid] < key) lo = mid + 1; else hi = mid; }
        bnd[tid] = lo;
    }
    __syncthreads();
    const int start = bnd[0];
    const int cnt   = bnd[1] - start;

    // fold pass0 partials -> z0
    const float* pb = part + (size_t)s * CPS * PSTR;
    float z = 0.f;
    if (tid < D) {
#pragma unroll
        for (int kk = 0; kk < CPS; ++kk) z += pb[kk * PSTR + tid];
    }
    if (tid == 0) {
        float st = 0.f;
#pragma unroll
        for (int kk = 0; kk < CPS; ++kk) st += pb[kk * PSTR + D];
        red[0] = 1.f / (st + 1e-16f);
    }
    __syncthreads();
    z *= red[0];

    float Scol = 0.f;   // running S for column tid (tid < D)
    float zr[8];

    for (int ph = 1; ph <= 3; ++ph) {
        // ---- energy + squash; S += squash(z) ----
        float e = (tid < D) ? z * z : 0.f;
#pragma unroll
        for (int o = 32; o; o >>= 1) e += __shfl_xor(e, o);
        if ((tid & 63) == 0) red_e[wv] = e;
        __syncthreads();
        if (tid == 0) {
            float E = 0.f;
#pragma unroll
            for (int h = 0; h < 16; ++h) E += red_e[h];
            red[1] = (E > 0.f) ? (sqrtf(E) / (1.f + E)) : 0.f;
        }
        __syncthreads();
        if (tid < D) { Scol += z * red[1]; zs[tid] = Scol; }
        __syncthreads();
#pragma unroll
        for (int j = 0; j < 8; ++j) zr[j] = zs[l * 8 + j];

        // ---- weighted stream over segment rows (1-ahead prefetch) ----
        float za[8] = {0,0,0,0,0,0,0,0};
        float s_acc = 0.f;
        int r = slot;
        uint4 ucur = make_uint4(0,0,0,0);
        float4 c0 = {0,0,0,0}, c1 = {0,0,0,0};
        if (r < cnt) {
            const size_t o = (size_t)(start + r) * D + l * 8;
            if (USE_WS) ucur = *(const uint4*)(xb + o);
            else { c0 = *(const float4*)(x + o); c1 = *(const float4*)(x + o + 4); }
        }
        while (r < cnt) {
            const int rn = r + SLOTS;
            uint4 unxt = make_uint4(0,0,0,0);
            float4 n0 = {0,0,0,0}, n1 = {0,0,0,0};
            if (rn < cnt) {
                const size_t o = (size_t)(start + rn) * D + l * 8;
                if (USE_WS) unxt = *(const uint4*)(xb + o);
                else { n0 = *(const float4*)(x + o); n1 = *(const float4*)(x + o + 4); }
            }
            float xf[8];
            if (USE_WS) {
                xf[0]=bflo(ucur.x); xf[1]=bfhi(ucur.x); xf[2]=bflo(ucur.y); xf[3]=bfhi(ucur.y);
                xf[4]=bflo(ucur.z); xf[5]=bfhi(ucur.z); xf[6]=bflo(ucur.w); xf[7]=bfhi(ucur.w);
            } else {
                xf[0]=c0.x; xf[1]=c0.y; xf[2]=c0.z; xf[3]=c0.w;
                xf[4]=c1.x; xf[5]=c1.y; xf[6]=c1.z; xf[7]=c1.w;
            }
            float dt = 0.f;
#pragma unroll
            for (int j = 0; j < 8; ++j) dt += xf[j] * zr[j];
#pragma unroll
            for (int o = 16; o; o >>= 1) dt += __shfl_xor(dt, o);   // 32-lane half
            const float w = __expf(dt);
            s_acc += w;
#pragma unroll
            for (int j = 0; j < 8; ++j) za[j] += w * xf[j];
            ucur = unxt; c0 = n0; c1 = n1; r = rn;
        }

        // ---- in-block fold: 32 slots -> z ----
#pragma unroll
        for (int j = 0; j < 8; ++j) zp[slot][l * 8 + j] = za[j];
        if (l == 0) sp[slot] = s_acc;
        __syncthreads();
        z = 0.f;
        if (tid < D) {
#pragma unroll
            for (int h = 0; h < SLOTS; ++h) z += zp[h][tid];
        }
        if (tid == 0) {
            float st = 0.f;
#pragma unroll
            for (int h = 0; h < SLOTS; ++h) st += sp[h];
            red[0] = 1.f / (st + 1e-16f);
        }
        __syncthreads();
        z *= red[0];
    }

    if (tid < D) out[(size_t)s * D + tid] = z;
}

extern "C" void kernel_launch(void* const* d_in, const int* in_sizes, int n_in,
                              void* d_out, int out_size, void* d_ws, size_t ws_size,
                              hipStream_t stream) {
    const float* x   = (const float*)d_in[0];
    const int* batch = (const int*)d_in[1];
    float* out       = (float*)d_out;
    const int n = in_sizes[1];          // 262144
    const int B = out_size / D;         // 512

    const size_t xb_bytes = (size_t)n * D * sizeof(unsigned short);      // 134 MB
    const size_t pe = (size_t)B * CPS * PSTR;                            // partials
    const bool use_ws = ws_size >= xb_bytes + pe * sizeof(float);

    unsigned short* xb = (unsigned short*)d_ws;
    float* pA = use_ws ? (float*)((char*)d_ws + xb_bytes) : (float*)d_ws;

    if (use_ws) {
        pass0_k<1><<<B * CPS, TPB0, 0, stream>>>(x, xb, batch, pA, n);
        phases_k<1><<<B, TPB1, 0, stream>>>(x, xb, batch, pA, out, n);
    } else {
        pass0_k<0><<<B * CPS, TPB0, 0, stream>>>(x, xb, batch, pA, n);
        phases_k<0><<<B, TPB1, 0, stream>>>(x, xb, batch, pA, out, n);
    }
}